// Round 6
// baseline (103.955 us; speedup 1.0000x reference)
//
#include <hip/hip_runtime.h>

// x     [B=32, I=64, K=8192]        f32
// U_in  [I=64, R=8,  K=8192, H=4]   f32  -> float4 per (i,r,k)
// M     [R=8,  S=8,  K=8192, H=4]   f32
// U_out [O=64, S=8,  K=8192, H=4]   f32
// out   [B=32, O=64, K=8192]        f32
//
// Round 6: LDS-read-instruction bound fix. Block = 512 thr = 16 kk x 2 rowhalf
// x 16 bslot, 2 b per thread (b=bs, bs+16). Each thread handles only its half
// of each chunk's rows (stage1: 4 of 8 ii; stage3: 4 of 8 o), each ds_read_b128
// feeds 2 b -> per-wave ds_read count drops 1088 -> 640. Stage-1 i-split fixed
// by one shfl_xor(16) 64-float reduction (in-wave pair = opposite half).
// Grid 512, R=4 LDS ring (64 KB), 2 blocks/CU = 16 waves/CU, VGPR capped 128.
// Staging/x/store counts per phase identical to round 5 -> same vmcnt schedule.

static constexpr int IN_CH  = 64;
static constexpr int OUT_CH = 64;
static constexpr int RANK   = 8;
static constexpr int MODES  = 8192;
static constexpr int KT     = 16;            // k per block
static constexpr int CROWS  = 64;            // rows per chunk
static constexpr int CF4    = CROWS * KT;    // 1024 float4 = 16 KB per chunk

typedef const __attribute__((address_space(1))) void* gas_t;
typedef __attribute__((address_space(3))) void* las_t;

#define FENCE asm volatile("" ::: "memory")

__device__ __forceinline__ void fma_s4(float4& a, const float4 w, const float v) {
    a.x = fmaf(w.x, v, a.x); a.y = fmaf(w.y, v, a.y);
    a.z = fmaf(w.z, v, a.z); a.w = fmaf(w.w, v, a.w);
}
__device__ __forceinline__ void fma_44(float4& a, const float4 w, const float4 v) {
    a.x = fmaf(w.x, v.x, a.x); a.y = fmaf(w.y, v.y, a.y);
    a.z = fmaf(w.z, v.z, a.z); a.w = fmaf(w.w, v.w, a.w);
}

// 8-wave staging: wave w loads rows [8w, 8w+8) of a [64 rows][16 kk] float4
// chunk with 2 global_load_lds_dwordx4 (1 KB each; wave-uniform LDS base).
__device__ __forceinline__ void stage_chunk8(const float4* gbase, float4* lbuf,
                                             int wid, int lane) {
    const int sub = lane >> 4;       // 0..3 row within quad
    const int col = lane & 15;       // 0..15 kk
#pragma unroll
    for (int j = 0; j < 2; ++j) {
        const int row0 = wid * 8 + j * 4;                        // wave-uniform
        const float4* src = gbase + (size_t)(row0 + sub) * MODES + col;
        float4* dst = lbuf + row0 * KT;                          // wave-uniform
        __builtin_amdgcn_global_load_lds((gas_t)src, (las_t)dst, 16, 0, 0);
    }
}

__global__ __launch_bounds__(512, 4) void diag_lr_fused(
    const float*  __restrict__ x,
    const float4* __restrict__ Uin,
    const float4* __restrict__ Mw,
    const float4* __restrict__ Uout,
    float*        __restrict__ out)
{
    __shared__ float4 lds[4][CF4];   // 64 KB ring

    const int t    = threadIdx.x;
    const int kk   = t & 15;
    const int half = (t >> 4) & 1;   // row-half within each chunk
    const int bs   = t >> 5;         // 0..15
    const int lane = t & 63;         // = kk | half<<4 | (bs&1)<<5
    const int wid  = t >> 6;         // 0..7
    const int k0   = blockIdx.x * KT;
    const int k    = k0 + kk;
    const int h4   = half * 4;       // first local row (ii or o) of my half

    const float4* UinB = Uin  + k0;  // row p -> + p*MODES
    const float4* MB   = Mw   + k0;
    const float4* UoB  = Uout + k0;
    const float*  xp0 = x   + (size_t)bs        * (IN_CH  * MODES) + k;
    const float*  xp1 = x   + (size_t)(bs + 16) * (IN_CH  * MODES) + k;
    float*        op0 = out + (size_t)bs        * (OUT_CH * MODES) + k;
    float*        op1 = out + (size_t)(bs + 16) * (OUT_CH * MODES) + k;

#define CHUNK_PTR(cc) ((cc) < 8 ? (UinB + (size_t)(cc) * CROWS * MODES) \
                     : (cc) == 8 ? MB \
                     : (UoB + (size_t)((cc) - 9) * CROWS * MODES))

    float xa[2][4][2];               // [buf][iil][b-half], static indices only

    // ---- prologue: queue order [s0(2), x0(8), s1(2)] ----
    stage_chunk8(CHUNK_PTR(0), &lds[0][0], wid, lane);
    FENCE;
#pragma unroll
    for (int ii = 0; ii < 4; ++ii) {
        xa[0][ii][0] = xp0[(h4 + ii) * MODES];
        xa[0][ii][1] = xp1[(h4 + ii) * MODES];
    }
    FENCE;
    stage_chunk8(CHUNK_PTR(1), &lds[1][0], wid, lane);
    FENCE;

    float4 r0[RANK], r1[RANK];
#pragma unroll
    for (int r = 0; r < RANK; ++r) {
        r0[r] = make_float4(0.f, 0.f, 0.f, 0.f);
        r1[r] = make_float4(0.f, 0.f, 0.f, 0.f);
    }

    // ---- phases 0..7: U_in (partial racc over my half's ii) ----
#pragma unroll
    for (int c = 0; c < 8; ++c) {
        asm volatile("s_waitcnt vmcnt(2)" ::: "memory");  // s(c), x(c) landed
        __builtin_amdgcn_s_barrier();
        FENCE;
        if (c < 7) {                                      // x(c+1) first,
#pragma unroll
            for (int ii = 0; ii < 4; ++ii) {
                xa[(c + 1) & 1][ii][0] = xp0[((c + 1) * 8 + h4 + ii) * MODES];
                xa[(c + 1) & 1][ii][1] = xp1[((c + 1) * 8 + h4 + ii) * MODES];
            }
            FENCE;
        }
        stage_chunk8(CHUNK_PTR(c + 2), &lds[(c + 2) & 3][0], wid, lane); // then stage
        FENCE;
        const float4* Lb = &lds[c & 3][0];
#pragma unroll
        for (int ii = 0; ii < 4; ++ii) {
            const float xv0 = xa[c & 1][ii][0];
            const float xv1 = xa[c & 1][ii][1];
#pragma unroll
            for (int r = 0; r < RANK; ++r) {
                const float4 w = Lb[((h4 + ii) * 8 + r) * KT + kk];
                fma_s4(r0[r], w, xv0);
                fma_s4(r1[r], w, xv1);
            }
        }
        FENCE;
    }

    // ---- cross-half reduction: pair lane = lane ^ 16 (same kk, same bs) ----
#pragma unroll
    for (int r = 0; r < RANK; ++r) {
        r0[r].x += __shfl_xor(r0[r].x, 16); r0[r].y += __shfl_xor(r0[r].y, 16);
        r0[r].z += __shfl_xor(r0[r].z, 16); r0[r].w += __shfl_xor(r0[r].w, 16);
        r1[r].x += __shfl_xor(r1[r].x, 16); r1[r].y += __shfl_xor(r1[r].y, 16);
        r1[r].z += __shfl_xor(r1[r].z, 16); r1[r].w += __shfl_xor(r1[r].w, 16);
    }

    // ---- phase 8: M (lds[0]); full sacc per thread (both halves duplicate) ----
    float4 s0[RANK], s1[RANK];
#pragma unroll
    for (int s = 0; s < RANK; ++s) {
        s0[s] = make_float4(0.f, 0.f, 0.f, 0.f);
        s1[s] = make_float4(0.f, 0.f, 0.f, 0.f);
    }
    {
        asm volatile("s_waitcnt vmcnt(2)" ::: "memory");  // s8 landed, keep s9
        __builtin_amdgcn_s_barrier();
        FENCE;
        stage_chunk8(CHUNK_PTR(10), &lds[10 & 3][0], wid, lane);
        FENCE;
        const float4* Lb = &lds[8 & 3][0];
#pragma unroll
        for (int r = 0; r < RANK; ++r)
#pragma unroll
            for (int s = 0; s < RANK; ++s) {
                const float4 w = Lb[(r * 8 + s) * KT + kk];
                fma_44(s0[s], w, r0[r]);
                fma_44(s1[s], w, r1[r]);
            }
        FENCE;
    }

    // ---- phases 9..16: U_out (my half's 4 o per chunk; no reduction needed) ----
#pragma unroll
    for (int c = 9; c < 17; ++c) {
        // queue at wait (instr units): ph9 [s9,s10]->keep 2; ph10 [s10,s11,st9]
        // ->keep 10; ph11-15 [s(c),st(c-2),s(c+1),st(c-1)]->keep 18;
        // ph16 [st13,s16,st14,st15]->keep 16.   (stores = 8/phase, same as r5)
        if      (c == 9)  asm volatile("s_waitcnt vmcnt(2)"  ::: "memory");
        else if (c == 10) asm volatile("s_waitcnt vmcnt(10)" ::: "memory");
        else if (c == 16) asm volatile("s_waitcnt vmcnt(16)" ::: "memory");
        else              asm volatile("s_waitcnt vmcnt(18)" ::: "memory");
        __builtin_amdgcn_s_barrier();
        FENCE;
        if (c + 2 <= 16) {
            stage_chunk8(CHUNK_PTR(c + 2), &lds[(c + 2) & 3][0], wid, lane);
            FENCE;
        }
        const float4* Lb = &lds[c & 3][0];
        const int oc = c - 9;
#pragma unroll
        for (int oo = 0; oo < 4; ++oo) {
            float4 a0 = make_float4(0.f, 0.f, 0.f, 0.f);
            float4 a1 = make_float4(0.f, 0.f, 0.f, 0.f);
#pragma unroll
            for (int s = 0; s < RANK; ++s) {
                const float4 w = Lb[((h4 + oo) * 8 + s) * KT + kk];
                fma_44(a0, w, s0[s]);
                fma_44(a1, w, s1[s]);
            }
            const int o = oc * 8 + h4 + oo;
            op0[o * MODES] = (a0.x + a0.y) + (a0.z + a0.w);
            op1[o * MODES] = (a1.x + a1.y) + (a1.z + a1.w);
        }
        FENCE;
    }
#undef CHUNK_PTR
}

extern "C" void kernel_launch(void* const* d_in, const int* in_sizes, int n_in,
                              void* d_out, int out_size, void* d_ws, size_t ws_size,
                              hipStream_t stream) {
    const float*  x    = (const float*)d_in[0];
    const float4* Uin  = (const float4*)d_in[1];
    const float4* Mw   = (const float4*)d_in[2];
    const float4* Uout = (const float4*)d_in[3];
    float* out = (float*)d_out;

    dim3 grid(512), block(512);
    hipLaunchKernelGGL(diag_lr_fused, grid, block, 0, stream, x, Uin, Mw, Uout, out);
}

// Round 7
// 92.814 us; speedup vs baseline: 1.1200x; 1.1200x over previous
//
#include <hip/hip_runtime.h>

// x     [B=32, I=64, K=8192]        f32
// U_in  [I=64, R=8,  K=8192, H=4]   f32  -> float4 per (i,r,k)
// M     [R=8,  S=8,  K=8192, H=4]   f32
// U_out [O=64, S=8,  K=8192, H=4]   f32
// out   [B=32, O=64, K=8192]        f32
//
// Round 7 = round 6 geometry (512 thr = 16 kk x 2 rowhalf x 16 bslot, 2 b per
// thread, grid 512, R=4 LDS ring, 1 barrier/phase, counted vmcnt) with the
// register peak fixed:
//  - NO cross-half reduction of r. Each half keeps partial r; s is computed
//    from partial r (linear), and ONE shfl_xor(16) reduction runs on s.
//  - M phase = two sequential per-b loops (s0 from r0, then s1 from r1) with
//    a memory-clobber fence between, so r0 dies while s0 builds: live peak
//    ~96 VGPR instead of r6's ~160 (which spilled: WRITE 2x, FETCH +37MB).

static constexpr int IN_CH  = 64;
static constexpr int OUT_CH = 64;
static constexpr int RANK   = 8;
static constexpr int MODES  = 8192;
static constexpr int KT     = 16;            // k per block
static constexpr int CROWS  = 64;            // rows per chunk
static constexpr int CF4    = CROWS * KT;    // 1024 float4 = 16 KB per chunk

typedef const __attribute__((address_space(1))) void* gas_t;
typedef __attribute__((address_space(3))) void* las_t;

#define FENCE asm volatile("" ::: "memory")

__device__ __forceinline__ void fma_s4(float4& a, const float4 w, const float v) {
    a.x = fmaf(w.x, v, a.x); a.y = fmaf(w.y, v, a.y);
    a.z = fmaf(w.z, v, a.z); a.w = fmaf(w.w, v, a.w);
}
__device__ __forceinline__ void fma_44(float4& a, const float4 w, const float4 v) {
    a.x = fmaf(w.x, v.x, a.x); a.y = fmaf(w.y, v.y, a.y);
    a.z = fmaf(w.z, v.z, a.z); a.w = fmaf(w.w, v.w, a.w);
}

// 8-wave staging: wave w loads rows [8w, 8w+8) of a [64 rows][16 kk] float4
// chunk with 2 global_load_lds_dwordx4 (1 KB each; wave-uniform LDS base).
__device__ __forceinline__ void stage_chunk8(const float4* gbase, float4* lbuf,
                                             int wid, int lane) {
    const int sub = lane >> 4;       // 0..3 row within quad
    const int col = lane & 15;       // 0..15 kk
#pragma unroll
    for (int j = 0; j < 2; ++j) {
        const int row0 = wid * 8 + j * 4;                        // wave-uniform
        const float4* src = gbase + (size_t)(row0 + sub) * MODES + col;
        float4* dst = lbuf + row0 * KT;                          // wave-uniform
        __builtin_amdgcn_global_load_lds((gas_t)src, (las_t)dst, 16, 0, 0);
    }
}

__global__ __launch_bounds__(512, 4) void diag_lr_fused(
    const float*  __restrict__ x,
    const float4* __restrict__ Uin,
    const float4* __restrict__ Mw,
    const float4* __restrict__ Uout,
    float*        __restrict__ out)
{
    __shared__ float4 lds[4][CF4];   // 64 KB ring

    const int t    = threadIdx.x;
    const int kk   = t & 15;
    const int half = (t >> 4) & 1;   // row-half within each chunk
    const int bs   = t >> 5;         // 0..15
    const int lane = t & 63;         // = kk | half<<4 | (bs&1)<<5
    const int wid  = t >> 6;         // 0..7
    const int k0   = blockIdx.x * KT;
    const int k    = k0 + kk;
    const int h4   = half * 4;       // first local row (ii or o) of my half

    const float4* UinB = Uin  + k0;  // row p -> + p*MODES
    const float4* MB   = Mw   + k0;
    const float4* UoB  = Uout + k0;
    const float*  xp0 = x   + (size_t)bs        * (IN_CH  * MODES) + k;
    const float*  xp1 = x   + (size_t)(bs + 16) * (IN_CH  * MODES) + k;
    float*        op0 = out + (size_t)bs        * (OUT_CH * MODES) + k;
    float*        op1 = out + (size_t)(bs + 16) * (OUT_CH * MODES) + k;

#define CHUNK_PTR(cc) ((cc) < 8 ? (UinB + (size_t)(cc) * CROWS * MODES) \
                     : (cc) == 8 ? MB \
                     : (UoB + (size_t)((cc) - 9) * CROWS * MODES))

    float xa[2][4][2];               // [buf][iil][b-half], static indices only

    // ---- prologue: queue order [s0(2), x0(8), s1(2)] ----
    stage_chunk8(CHUNK_PTR(0), &lds[0][0], wid, lane);
    FENCE;
#pragma unroll
    for (int ii = 0; ii < 4; ++ii) {
        xa[0][ii][0] = xp0[(h4 + ii) * MODES];
        xa[0][ii][1] = xp1[(h4 + ii) * MODES];
    }
    FENCE;
    stage_chunk8(CHUNK_PTR(1), &lds[1][0], wid, lane);
    FENCE;

    float4 r0[RANK], r1[RANK];       // PARTIAL r (my ii-half only)
#pragma unroll
    for (int r = 0; r < RANK; ++r) {
        r0[r] = make_float4(0.f, 0.f, 0.f, 0.f);
        r1[r] = make_float4(0.f, 0.f, 0.f, 0.f);
    }

    // ---- phases 0..7: U_in (partial racc over my half's ii) ----
#pragma unroll
    for (int c = 0; c < 8; ++c) {
        asm volatile("s_waitcnt vmcnt(2)" ::: "memory");  // s(c), x(c) landed
        __builtin_amdgcn_s_barrier();
        FENCE;
        if (c < 7) {                                      // x(c+1) first,
#pragma unroll
            for (int ii = 0; ii < 4; ++ii) {
                xa[(c + 1) & 1][ii][0] = xp0[((c + 1) * 8 + h4 + ii) * MODES];
                xa[(c + 1) & 1][ii][1] = xp1[((c + 1) * 8 + h4 + ii) * MODES];
            }
            FENCE;
        }
        stage_chunk8(CHUNK_PTR(c + 2), &lds[(c + 2) & 3][0], wid, lane); // then stage
        FENCE;
        const float4* Lb = &lds[c & 3][0];
#pragma unroll
        for (int ii = 0; ii < 4; ++ii) {
            const float xv0 = xa[c & 1][ii][0];
            const float xv1 = xa[c & 1][ii][1];
#pragma unroll
            for (int r = 0; r < RANK; ++r) {
                const float4 w = Lb[((h4 + ii) * 8 + r) * KT + kk];
                fma_s4(r0[r], w, xv0);
                fma_s4(r1[r], w, xv1);
            }
        }
        FENCE;
    }

    // ---- phase 8: M (lds[0]); partial s from partial r, b-sequential ----
    float4 s0[RANK], s1[RANK];
    {
        asm volatile("s_waitcnt vmcnt(2)" ::: "memory");  // s8 landed, keep s9
        __builtin_amdgcn_s_barrier();
        FENCE;
        stage_chunk8(CHUNK_PTR(10), &lds[10 & 3][0], wid, lane);
        FENCE;
        const float4* Lb = &lds[8 & 3][0];
        // loop 1: s0 from r0 (r0[r] dies as it's consumed; r1 untouched)
#pragma unroll
        for (int s = 0; s < RANK; ++s) s0[s] = make_float4(0.f, 0.f, 0.f, 0.f);
#pragma unroll
        for (int r = 0; r < RANK; ++r)
#pragma unroll
            for (int s = 0; s < RANK; ++s)
                fma_44(s0[s], Lb[(r * 8 + s) * KT + kk], r0[r]);
        FENCE;  // block CSE-merge of the two M-read loops (keeps peak ~96 VGPR)
        // loop 2: s1 from r1
#pragma unroll
        for (int s = 0; s < RANK; ++s) s1[s] = make_float4(0.f, 0.f, 0.f, 0.f);
#pragma unroll
        for (int r = 0; r < RANK; ++r)
#pragma unroll
            for (int s = 0; s < RANK; ++s)
                fma_44(s1[s], Lb[(r * 8 + s) * KT + kk], r1[r]);
        FENCE;
    }

    // ---- cross-half reduction ON S: pair lane = lane ^ 16 (same kk, bs) ----
#pragma unroll
    for (int s = 0; s < RANK; ++s) {
        s0[s].x += __shfl_xor(s0[s].x, 16); s0[s].y += __shfl_xor(s0[s].y, 16);
        s0[s].z += __shfl_xor(s0[s].z, 16); s0[s].w += __shfl_xor(s0[s].w, 16);
        s1[s].x += __shfl_xor(s1[s].x, 16); s1[s].y += __shfl_xor(s1[s].y, 16);
        s1[s].z += __shfl_xor(s1[s].z, 16); s1[s].w += __shfl_xor(s1[s].w, 16);
    }

    // ---- phases 9..16: U_out (my half's 4 o per chunk; no reduction) ----
#pragma unroll
    for (int c = 9; c < 17; ++c) {
        // queue at wait (instr units): ph9 [s9,s10]->keep 2; ph10 [s10,s11,st9]
        // ->keep 10; ph11-15 [s(c),st(c-2),s(c+1),st(c-1)]->keep 18;
        // ph16 [st13,s16,st14,st15]->keep 16.   (stores = 8/phase)
        if      (c == 9)  asm volatile("s_waitcnt vmcnt(2)"  ::: "memory");
        else if (c == 10) asm volatile("s_waitcnt vmcnt(10)" ::: "memory");
        else if (c == 16) asm volatile("s_waitcnt vmcnt(16)" ::: "memory");
        else              asm volatile("s_waitcnt vmcnt(18)" ::: "memory");
        __builtin_amdgcn_s_barrier();
        FENCE;
        if (c + 2 <= 16) {
            stage_chunk8(CHUNK_PTR(c + 2), &lds[(c + 2) & 3][0], wid, lane);
            FENCE;
        }
        const float4* Lb = &lds[c & 3][0];
        const int oc = c - 9;
#pragma unroll
        for (int oo = 0; oo < 4; ++oo) {
            float4 a0 = make_float4(0.f, 0.f, 0.f, 0.f);
            float4 a1 = make_float4(0.f, 0.f, 0.f, 0.f);
#pragma unroll
            for (int s = 0; s < RANK; ++s) {
                const float4 w = Lb[((h4 + oo) * 8 + s) * KT + kk];
                fma_44(a0, w, s0[s]);
                fma_44(a1, w, s1[s]);
            }
            const int o = oc * 8 + h4 + oo;
            op0[o * MODES] = (a0.x + a0.y) + (a0.z + a0.w);
            op1[o * MODES] = (a1.x + a1.y) + (a1.z + a1.w);
        }
        FENCE;
    }
#undef CHUNK_PTR
}

extern "C" void kernel_launch(void* const* d_in, const int* in_sizes, int n_in,
                              void* d_out, int out_size, void* d_ws, size_t ws_size,
                              hipStream_t stream) {
    const float*  x    = (const float*)d_in[0];
    const float4* Uin  = (const float4*)d_in[1];
    const float4* Mw   = (const float4*)d_in[2];
    const float4* Uout = (const float4*)d_in[3];
    float* out = (float*)d_out;

    dim3 grid(512), block(512);
    hipLaunchKernelGGL(diag_lr_fused, grid, block, 0, stream, x, Uin, Mw, Uout, out);
}

// Round 8
// 84.950 us; speedup vs baseline: 1.2237x; 1.0926x over previous
//
#include <hip/hip_runtime.h>

// x     [B=32, I=64, K=8192]        f32
// U_in  [I=64, R=8,  K=8192, H=4]   f32  -> float4 per (i,r,k)
// M     [R=8,  S=8,  K=8192, H=4]   f32
// U_out [O=64, S=8,  K=8192, H=4]   f32
// out   [B=32, O=64, K=8192]        f32
//
// Round 8 = round 7 with ONE change: __launch_bounds__(512, 2) instead of
// (512, 4). Rounds 5-7 all allocated exactly 64 VGPR (= 512/8), and rounds
// 6-7 spilled (WRITE 2x) at ~110 live regs -> the (512,4) bound was capping
// VGPRs at 64, not 128. (512,2) raises the cap to >=128 under either
// launch_bounds semantics; real occupancy is LDS-limited at 2 blocks/CU
// (2 x 64 KB ring) = 16 waves/CU either way.
//
// Geometry: 512 thr = 16 kk x 2 rowhalf x 16 bslot, 2 b per thread
// (b = bs, bs+16); each thread reads only its half of each chunk's rows
// (stage1: 4 of 8 ii; stage3: 4 of 8 o) -> 640 ds_read_b128/thread vs 1088.
// Partial r per half; s computed from partial r (linearity), single
// shfl_xor(16) reduction on s. 17 chunks through R=4 LDS ring staged 2 ahead
// via global_load_lds, ONE barrier/phase, counted vmcnt (never 0 mid-loop).

static constexpr int IN_CH  = 64;
static constexpr int OUT_CH = 64;
static constexpr int RANK   = 8;
static constexpr int MODES  = 8192;
static constexpr int KT     = 16;            // k per block
static constexpr int CROWS  = 64;            // rows per chunk
static constexpr int CF4    = CROWS * KT;    // 1024 float4 = 16 KB per chunk

typedef const __attribute__((address_space(1))) void* gas_t;
typedef __attribute__((address_space(3))) void* las_t;

#define FENCE asm volatile("" ::: "memory")

__device__ __forceinline__ void fma_s4(float4& a, const float4 w, const float v) {
    a.x = fmaf(w.x, v, a.x); a.y = fmaf(w.y, v, a.y);
    a.z = fmaf(w.z, v, a.z); a.w = fmaf(w.w, v, a.w);
}
__device__ __forceinline__ void fma_44(float4& a, const float4 w, const float4 v) {
    a.x = fmaf(w.x, v.x, a.x); a.y = fmaf(w.y, v.y, a.y);
    a.z = fmaf(w.z, v.z, a.z); a.w = fmaf(w.w, v.w, a.w);
}

// 8-wave staging: wave w loads rows [8w, 8w+8) of a [64 rows][16 kk] float4
// chunk with 2 global_load_lds_dwordx4 (1 KB each; wave-uniform LDS base).
__device__ __forceinline__ void stage_chunk8(const float4* gbase, float4* lbuf,
                                             int wid, int lane) {
    const int sub = lane >> 4;       // 0..3 row within quad
    const int col = lane & 15;       // 0..15 kk
#pragma unroll
    for (int j = 0; j < 2; ++j) {
        const int row0 = wid * 8 + j * 4;                        // wave-uniform
        const float4* src = gbase + (size_t)(row0 + sub) * MODES + col;
        float4* dst = lbuf + row0 * KT;                          // wave-uniform
        __builtin_amdgcn_global_load_lds((gas_t)src, (las_t)dst, 16, 0, 0);
    }
}

__global__ __launch_bounds__(512, 2) void diag_lr_fused(
    const float*  __restrict__ x,
    const float4* __restrict__ Uin,
    const float4* __restrict__ Mw,
    const float4* __restrict__ Uout,
    float*        __restrict__ out)
{
    __shared__ float4 lds[4][CF4];   // 64 KB ring

    const int t    = threadIdx.x;
    const int kk   = t & 15;
    const int half = (t >> 4) & 1;   // row-half within each chunk
    const int bs   = t >> 5;         // 0..15
    const int lane = t & 63;         // = kk | half<<4 | (bs&1)<<5
    const int wid  = t >> 6;         // 0..7
    const int k0   = blockIdx.x * KT;
    const int k    = k0 + kk;
    const int h4   = half * 4;       // first local row (ii or o) of my half

    const float4* UinB = Uin  + k0;  // row p -> + p*MODES
    const float4* MB   = Mw   + k0;
    const float4* UoB  = Uout + k0;
    const float*  xp0 = x   + (size_t)bs        * (IN_CH  * MODES) + k;
    const float*  xp1 = x   + (size_t)(bs + 16) * (IN_CH  * MODES) + k;
    float*        op0 = out + (size_t)bs        * (OUT_CH * MODES) + k;
    float*        op1 = out + (size_t)(bs + 16) * (OUT_CH * MODES) + k;

#define CHUNK_PTR(cc) ((cc) < 8 ? (UinB + (size_t)(cc) * CROWS * MODES) \
                     : (cc) == 8 ? MB \
                     : (UoB + (size_t)((cc) - 9) * CROWS * MODES))

    float xa[2][4][2];               // [buf][iil][b-half], static indices only

    // ---- prologue: queue order [s0(2), x0(8), s1(2)] ----
    stage_chunk8(CHUNK_PTR(0), &lds[0][0], wid, lane);
    FENCE;
#pragma unroll
    for (int ii = 0; ii < 4; ++ii) {
        xa[0][ii][0] = xp0[(h4 + ii) * MODES];
        xa[0][ii][1] = xp1[(h4 + ii) * MODES];
    }
    FENCE;
    stage_chunk8(CHUNK_PTR(1), &lds[1][0], wid, lane);
    FENCE;

    float4 r0[RANK], r1[RANK];       // PARTIAL r (my ii-half only)
#pragma unroll
    for (int r = 0; r < RANK; ++r) {
        r0[r] = make_float4(0.f, 0.f, 0.f, 0.f);
        r1[r] = make_float4(0.f, 0.f, 0.f, 0.f);
    }

    // ---- phases 0..7: U_in (partial racc over my half's ii) ----
#pragma unroll
    for (int c = 0; c < 8; ++c) {
        asm volatile("s_waitcnt vmcnt(2)" ::: "memory");  // s(c), x(c) landed
        __builtin_amdgcn_s_barrier();
        FENCE;
        if (c < 7) {                                      // x(c+1) first,
#pragma unroll
            for (int ii = 0; ii < 4; ++ii) {
                xa[(c + 1) & 1][ii][0] = xp0[((c + 1) * 8 + h4 + ii) * MODES];
                xa[(c + 1) & 1][ii][1] = xp1[((c + 1) * 8 + h4 + ii) * MODES];
            }
            FENCE;
        }
        stage_chunk8(CHUNK_PTR(c + 2), &lds[(c + 2) & 3][0], wid, lane); // then stage
        FENCE;
        const float4* Lb = &lds[c & 3][0];
#pragma unroll
        for (int ii = 0; ii < 4; ++ii) {
            const float xv0 = xa[c & 1][ii][0];
            const float xv1 = xa[c & 1][ii][1];
#pragma unroll
            for (int r = 0; r < RANK; ++r) {
                const float4 w = Lb[((h4 + ii) * 8 + r) * KT + kk];
                fma_s4(r0[r], w, xv0);
                fma_s4(r1[r], w, xv1);
            }
        }
        FENCE;
    }

    // ---- phase 8: M (lds[0]); partial s from partial r, b-sequential ----
    float4 s0[RANK], s1[RANK];
    {
        asm volatile("s_waitcnt vmcnt(2)" ::: "memory");  // s8 landed, keep s9
        __builtin_amdgcn_s_barrier();
        FENCE;
        stage_chunk8(CHUNK_PTR(10), &lds[10 & 3][0], wid, lane);
        FENCE;
        const float4* Lb = &lds[8 & 3][0];
        // loop 1: s0 from r0 (r0[r] dies as it's consumed; r1 untouched)
#pragma unroll
        for (int s = 0; s < RANK; ++s) s0[s] = make_float4(0.f, 0.f, 0.f, 0.f);
#pragma unroll
        for (int r = 0; r < RANK; ++r)
#pragma unroll
            for (int s = 0; s < RANK; ++s)
                fma_44(s0[s], Lb[(r * 8 + s) * KT + kk], r0[r]);
        FENCE;  // block CSE-merge of the two M-read loops (caps live range)
        // loop 2: s1 from r1
#pragma unroll
        for (int s = 0; s < RANK; ++s) s1[s] = make_float4(0.f, 0.f, 0.f, 0.f);
#pragma unroll
        for (int r = 0; r < RANK; ++r)
#pragma unroll
            for (int s = 0; s < RANK; ++s)
                fma_44(s1[s], Lb[(r * 8 + s) * KT + kk], r1[r]);
        FENCE;
    }

    // ---- cross-half reduction ON S: pair lane = lane ^ 16 (same kk, bs) ----
#pragma unroll
    for (int s = 0; s < RANK; ++s) {
        s0[s].x += __shfl_xor(s0[s].x, 16); s0[s].y += __shfl_xor(s0[s].y, 16);
        s0[s].z += __shfl_xor(s0[s].z, 16); s0[s].w += __shfl_xor(s0[s].w, 16);
        s1[s].x += __shfl_xor(s1[s].x, 16); s1[s].y += __shfl_xor(s1[s].y, 16);
        s1[s].z += __shfl_xor(s1[s].z, 16); s1[s].w += __shfl_xor(s1[s].w, 16);
    }

    // ---- phases 9..16: U_out (my half's 4 o per chunk; no reduction) ----
#pragma unroll
    for (int c = 9; c < 17; ++c) {
        // queue at wait (instr units): ph9 [s9,s10]->keep 2; ph10 [s10,s11,st9]
        // ->keep 10; ph11-15 [s(c),st(c-2),s(c+1),st(c-1)]->keep 18;
        // ph16 [st13,s16,st14,st15]->keep 16.   (stores = 8/phase)
        if      (c == 9)  asm volatile("s_waitcnt vmcnt(2)"  ::: "memory");
        else if (c == 10) asm volatile("s_waitcnt vmcnt(10)" ::: "memory");
        else if (c == 16) asm volatile("s_waitcnt vmcnt(16)" ::: "memory");
        else              asm volatile("s_waitcnt vmcnt(18)" ::: "memory");
        __builtin_amdgcn_s_barrier();
        FENCE;
        if (c + 2 <= 16) {
            stage_chunk8(CHUNK_PTR(c + 2), &lds[(c + 2) & 3][0], wid, lane);
            FENCE;
        }
        const float4* Lb = &lds[c & 3][0];
        const int oc = c - 9;
#pragma unroll
        for (int oo = 0; oo < 4; ++oo) {
            float4 a0 = make_float4(0.f, 0.f, 0.f, 0.f);
            float4 a1 = make_float4(0.f, 0.f, 0.f, 0.f);
#pragma unroll
            for (int s = 0; s < RANK; ++s) {
                const float4 w = Lb[((h4 + oo) * 8 + s) * KT + kk];
                fma_44(a0, w, s0[s]);
                fma_44(a1, w, s1[s]);
            }
            const int o = oc * 8 + h4 + oo;
            op0[o * MODES] = (a0.x + a0.y) + (a0.z + a0.w);
            op1[o * MODES] = (a1.x + a1.y) + (a1.z + a1.w);
        }
        FENCE;
    }
#undef CHUNK_PTR
}

extern "C" void kernel_launch(void* const* d_in, const int* in_sizes, int n_in,
                              void* d_out, int out_size, void* d_ws, size_t ws_size,
                              hipStream_t stream) {
    const float*  x    = (const float*)d_in[0];
    const float4* Uin  = (const float4*)d_in[1];
    const float4* Mw   = (const float4*)d_in[2];
    const float4* Uout = (const float4*)d_in[3];
    float* out = (float*)d_out;

    dim3 grid(512), block(512);
    hipLaunchKernelGGL(diag_lr_fused, grid, block, 0, stream, x, Uin, Mw, Uout, out);
}